// Round 4
// baseline (50.893 us; speedup 1.0000x reference)
//
#include <hip/hip_runtime.h>
#include <math.h>

// Problem constants
#define NB 16
#define NC 64
#define NL 4096            // 64*64
#define NCOUT 64
#define EPSF 1e-5f
#define LOG_EPSF -11.512925464970229f   // log(1e-5)
#define CC 4               // channels per chunk
#define NCHUNK 16

#define FMA_STEP(MV, AV, WM, WA)                                                      \
    accm[0].x = fmaf(MV.x, WM.x, accm[0].x); accm[0].y = fmaf(MV.y, WM.x, accm[0].y); \
    accm[0].z = fmaf(MV.z, WM.x, accm[0].z); accm[0].w = fmaf(MV.w, WM.x, accm[0].w); \
    accm[1].x = fmaf(MV.x, WM.y, accm[1].x); accm[1].y = fmaf(MV.y, WM.y, accm[1].y); \
    accm[1].z = fmaf(MV.z, WM.y, accm[1].z); accm[1].w = fmaf(MV.w, WM.y, accm[1].w); \
    accm[2].x = fmaf(MV.x, WM.z, accm[2].x); accm[2].y = fmaf(MV.y, WM.z, accm[2].y); \
    accm[2].z = fmaf(MV.z, WM.z, accm[2].z); accm[2].w = fmaf(MV.w, WM.z, accm[2].w); \
    accm[3].x = fmaf(MV.x, WM.w, accm[3].x); accm[3].y = fmaf(MV.y, WM.w, accm[3].y); \
    accm[3].z = fmaf(MV.z, WM.w, accm[3].z); accm[3].w = fmaf(MV.w, WM.w, accm[3].w); \
    acca[0].x = fmaf(AV.x, WA.x, acca[0].x); acca[0].y = fmaf(AV.y, WA.x, acca[0].y); \
    acca[0].z = fmaf(AV.z, WA.x, acca[0].z); acca[0].w = fmaf(AV.w, WA.x, acca[0].w); \
    acca[1].x = fmaf(AV.x, WA.y, acca[1].x); acca[1].y = fmaf(AV.y, WA.y, acca[1].y); \
    acca[1].z = fmaf(AV.z, WA.y, acca[1].z); acca[1].w = fmaf(AV.w, WA.y, acca[1].w); \
    acca[2].x = fmaf(AV.x, WA.z, acca[2].x); acca[2].y = fmaf(AV.y, WA.z, acca[2].y); \
    acca[2].z = fmaf(AV.z, WA.z, acca[2].z); acca[2].w = fmaf(AV.w, WA.z, acca[2].w); \
    acca[3].x = fmaf(AV.x, WA.w, acca[3].x); acca[3].y = fmaf(AV.y, WA.w, acca[3].y); \
    acca[3].z = fmaf(AV.z, WA.w, acca[3].z); acca[3].w = fmaf(AV.w, WA.w, acca[3].w);

__global__ __launch_bounds__(256, 3) void fused_kernel(
    const float* __restrict__ x_mag, const float* __restrict__ x_ang,
    const float* __restrict__ wm, const float* __restrict__ wa,
    const float* __restrict__ w1, const float* __restrict__ w2,
    float* __restrict__ out)
{
    __shared__ float lfm[CC][3][72];     // log(fm+eps), cols 3..68 valid (j+4)
    __shared__ float fas[CC][3][72];     // fa
    __shared__ float m1r[CC][64];        // conv outputs (mag)
    __shared__ float a1r[CC][64];        // conv outputs (ang)
    __shared__ float w2m[64][68];        // [c][o] w2^2/rowsum(o)
    __shared__ float w2a[64][68];        // [c][o] w2^2/globalsum
    __shared__ float wm1s[64][9];        // w1^2/rowsum(c)
    __shared__ float wa1s[64][9];        // w1^2/globalsum
    __shared__ float smag_s[64][9];      // class sums of nws_mag
    __shared__ float tang_s[64][9];      // class sums of nw_ang
    __shared__ float red[4][4];

    const int tid = threadIdx.x;
    const int lane = tid & 63;
    const int wv = tid >> 6;

    // XCD-aware swizzle (1024 % 8 == 0 -> simple bijection): each XCD gets a
    // contiguous 128-block range = 2 whole images -> halo rows L2-local.
    int bid = (blockIdx.x & 7) * 128 + (blockIdx.x >> 3);
    const int b = bid >> 6;
    const int i = bid & 63;              // image row owned by this block

    // ---------- stage-slot decode (fixed per thread) ----------
    // 384 f4 items per chunk: [0,192) mag, [192,384) ang.
    // slot0 = item tid ; slot1 = item tid+256 (tid<128, always ang)
    const bool mag0 = (tid < 192);
    const int m0 = mag0 ? tid : tid - 192;
    const int cl0 = m0 / 48;
    const int rm0 = m0 - cl0 * 48;
    const int r0 = rm0 >> 4, j40 = rm0 & 15;
    const int ir0 = i - 1 + r0;
    const bool ok0 = ((unsigned)ir0 < 64u);
    const float* sp0 = (mag0 ? x_mag : x_ang)
                     + ((size_t)(b * NC + cl0) * NL + (ok0 ? ir0 : 0) * 64 + j40 * 4);

    const bool has1 = (tid < 128);
    const int it1 = tid + 64;            // ang item index in [64,192)
    const int cl1 = it1 / 48;
    const int rm1 = it1 - cl1 * 48;
    const int r1 = rm1 >> 4, j41 = rm1 & 15;
    const int ir1 = i - 1 + r1;
    const bool ok1 = has1 && ((unsigned)ir1 < 64u);
    const float* sp1 = x_ang + ((size_t)(b * NC + cl1) * NL + (ok1 ? ir1 : 0) * 64 + j41 * 4);

    // issue chunk-0 prefetch immediately (hides under weight prep)
    float4 pf0 = *(const float4*)sp0;
    float4 pf1;
    if (has1) pf1 = *(const float4*)sp1;

    // hoisted per-thread class constants for slot0 (mag or ang) and slot1
    const int ci0 = (ir0 == 0) ? 0 : ((ir0 == 63) ? 2 : 1);
    const float ni0 = (ci0 == 1) ? 3.f : 2.f;
    const int kL0 = ci0 * 3 + 0, kC0 = ci0 * 3 + 1, kR0 = ci0 * 3 + 2;
    const float nC0 = 3.f * ni0;
    const float n00 = (j40 == 0) ? 2.f * ni0 : nC0;
    const float n30 = (j40 == 15) ? 2.f * ni0 : nC0;
    const int ci1 = (ir1 == 0) ? 0 : ((ir1 == 63) ? 2 : 1);
    const int kL1 = ci1 * 3 + 0, kC1 = ci1 * 3 + 1, kR1 = ci1 * 3 + 2;

    // ---------- per-block weight prep (redundant; inputs are L2/L3-hot) ----------
    float p0 = 0.f, p1 = 0.f, p2 = 0.f, p3 = 0.f;
    {
        float v;
        v = wm[tid];       p0 += v * v;  v = wm[tid + 256]; p0 += v * v;
        v = wa[tid];       p1 += v * v;  v = wa[tid + 256]; p1 += v * v;
        v = w1[tid];       p2 += v * v;  v = w1[tid + 256]; p2 += v * v;
        if (tid < 64) {
            v = wm[tid + 512]; p0 += v * v;
            v = wa[tid + 512]; p1 += v * v;
            v = w1[tid + 512]; p2 += v * v;
        }
    }
    float4 v4[4]; float rpart[4];
    #pragma unroll
    for (int k = 0; k < 4; ++k) {
        int q = tid + k * 256;
        v4[k] = ((const float4*)w2)[q];
        float d = fmaf(v4[k].x, v4[k].x, fmaf(v4[k].y, v4[k].y,
                  fmaf(v4[k].z, v4[k].z, v4[k].w * v4[k].w)));
        rpart[k] = d; p3 += d;
    }
    #pragma unroll
    for (int k = 0; k < 4; ++k) {
        float r = rpart[k];
        r += __shfl_xor(r, 1); r += __shfl_xor(r, 2);
        r += __shfl_xor(r, 4); r += __shfl_xor(r, 8);
        rpart[k] = r;                    // rowsum r2[o], broadcast in 16-group
    }
    #pragma unroll
    for (int s = 32; s; s >>= 1) {
        p0 += __shfl_down(p0, s); p1 += __shfl_down(p1, s);
        p2 += __shfl_down(p2, s); p3 += __shfl_down(p3, s);
    }
    if (lane == 0) { red[0][wv] = p0; red[1][wv] = p1; red[2][wv] = p2; red[3][wv] = p3; }
    __syncthreads();
    const float s_wm2 = red[0][0] + red[0][1] + red[0][2] + red[0][3];
    const float s_wa2 = red[1][0] + red[1][1] + red[1][2] + red[1][3];
    const float s_w12 = red[2][0] + red[2][1] + red[2][2] + red[2][3];
    const float inv_s22 = 1.f / (red[3][0] + red[3][1] + red[3][2] + red[3][3]);

    // w2 tables (transposed [c][o], normalized)
    #pragma unroll
    for (int k = 0; k < 4; ++k) {
        int q = tid + k * 256;
        int o = q >> 4, c4 = (q & 15) * 4;
        float inv_r = 1.f / rpart[k];
        float sx = v4[k].x * v4[k].x, sy = v4[k].y * v4[k].y;
        float sz = v4[k].z * v4[k].z, sw = v4[k].w * v4[k].w;
        w2m[c4 + 0][o] = sx * inv_r;  w2a[c4 + 0][o] = sx * inv_s22;
        w2m[c4 + 1][o] = sy * inv_r;  w2a[c4 + 1][o] = sy * inv_s22;
        w2m[c4 + 2][o] = sz * inv_r;  w2a[c4 + 2][o] = sz * inv_s22;
        w2m[c4 + 3][o] = sw * inv_r;  w2a[c4 + 3][o] = sw * inv_s22;
    }
    // w1 tables (wave 0) and boundary-class tables (wave 1)
    if (tid < 64) {
        const int c = tid;
        float q[9]; float r1c = 0.f;
        #pragma unroll
        for (int k = 0; k < 9; ++k) { float v = w1[c * 9 + k]; q[k] = v * v; r1c += q[k]; }
        float inv_r = 1.f / r1c, inv_s = 1.f / s_w12;
        #pragma unroll
        for (int k = 0; k < 9; ++k) { wm1s[c][k] = q[k] * inv_r; wa1s[c][k] = q[k] * inv_s; }
    } else if (tid < 128) {
        const int c = tid - 64;
        float nm[9], na[9];
        float inv_m = 1.f / s_wm2, inv_a = 1.f / s_wa2;
        #pragma unroll
        for (int k = 0; k < 9; ++k) {
            float v = wm[c * 9 + k];
            nm[k] = v * v * inv_m;
            na[k] = wa[c * 9 + k] * inv_a;
        }
        #pragma unroll
        for (int ci = 0; ci < 3; ++ci) {
            #pragma unroll
            for (int cj = 0; cj < 3; ++cj) {
                float sm = 0.f, sa = 0.f;
                #pragma unroll
                for (int ki = 0; ki < 3; ++ki) {
                    bool vi = (ci == 0) ? (ki < 2) : ((ci == 2) ? (ki > 0) : true);
                    if (!vi) continue;
                    #pragma unroll
                    for (int kj = 0; kj < 3; ++kj) {
                        bool vj = (cj == 0) ? (kj < 2) : ((cj == 2) ? (kj > 0) : true);
                        if (!vj) continue;
                        sm += nm[ki * 3 + kj];
                        sa += na[ki * 3 + kj];
                    }
                }
                smag_s[c][ci * 3 + cj] = sm;
                tang_s[c][ci * 3 + cj] = sa;
            }
        }
    }
    __syncthreads();

    // ---------- main channel loop ----------
    const int l0 = (tid & 15) * 4;
    const int o0 = (tid >> 4) * 4;
    const int cv_c = tid >> 6;           // conv: channel-in-chunk (wave id)
    const int cv_j = tid & 63;           // conv: pixel column

    float4 accm[4], acca[4];
    #pragma unroll
    for (int oi = 0; oi < 4; ++oi) {
        accm[oi].x = accm[oi].y = accm[oi].z = accm[oi].w = 0.f;
        acca[oi].x = acca[oi].y = acca[oi].z = acca[oi].w = 0.f;
    }

    for (int ch = 0; ch < NCHUNK; ++ch) {
        const int ch0 = ch * CC;

        // ---- stage: transform prefetched rows into LDS ----
        {
            const int c0g = ch0 + cl0;
            if (mag0) {
                float4 dv;
                if (ok0) {
                    float sC = smag_s[c0g][kC0];
                    float s0 = (j40 == 0)  ? smag_s[c0g][kL0] : sC;
                    float s3 = (j40 == 15) ? smag_s[c0g][kR0] : sC;
                    dv.x = __logf(fmaf(n00, pf0.x, s0) + EPSF);
                    dv.y = __logf(fmaf(nC0, pf0.y, sC) + EPSF);
                    dv.z = __logf(fmaf(nC0, pf0.z, sC) + EPSF);
                    dv.w = __logf(fmaf(n30, pf0.w, s3) + EPSF);
                } else {
                    dv.x = dv.y = dv.z = dv.w = LOG_EPSF;
                }
                *(float4*)&lfm[cl0][r0][4 + j40 * 4] = dv;
                if (j40 == 0)  lfm[cl0][r0][3]  = LOG_EPSF;
                if (j40 == 15) lfm[cl0][r0][68] = LOG_EPSF;
            } else {
                float4 dv;
                if (ok0) {
                    float tC = tang_s[c0g][kC0];
                    float t0 = (j40 == 0)  ? tang_s[c0g][kL0] : tC;
                    float t3 = (j40 == 15) ? tang_s[c0g][kR0] : tC;
                    dv.x = pf0.x * t0; dv.y = pf0.y * tC;
                    dv.z = pf0.z * tC; dv.w = pf0.w * t3;
                } else {
                    dv.x = dv.y = dv.z = dv.w = 0.f;
                }
                *(float4*)&fas[cl0][r0][4 + j40 * 4] = dv;
                if (j40 == 0)  fas[cl0][r0][3]  = 0.f;
                if (j40 == 15) fas[cl0][r0][68] = 0.f;
            }
            if (has1) {
                const int c1g = ch0 + cl1;
                float4 dv;
                if (ok1) {
                    float tC = tang_s[c1g][kC1];
                    float t0 = (j41 == 0)  ? tang_s[c1g][kL1] : tC;
                    float t3 = (j41 == 15) ? tang_s[c1g][kR1] : tC;
                    dv.x = pf1.x * t0; dv.y = pf1.y * tC;
                    dv.z = pf1.z * tC; dv.w = pf1.w * t3;
                } else {
                    dv.x = dv.y = dv.z = dv.w = 0.f;
                }
                *(float4*)&fas[cl1][r1][4 + j41 * 4] = dv;
                if (j41 == 0)  fas[cl1][r1][3]  = 0.f;
                if (j41 == 15) fas[cl1][r1][68] = 0.f;
            }
        }

        // ---- prefetch next chunk (in flight across conv + matmul) ----
        if (ch + 1 < NCHUNK) {
            const size_t adv = (size_t)(ch + 1) * CC * NL;
            pf0 = *(const float4*)(sp0 + adv);
            if (has1) pf1 = *(const float4*)(sp1 + adv);
        }
        __syncthreads();                 // lfm/fas ready

        // ---- conv: one pixel per thread, channel = wave ----
        {
            const int cg = ch0 + cv_c;
            float am = 0.f, aa = 0.f;
            #pragma unroll
            for (int r = 0; r < 3; ++r) {
                #pragma unroll
                for (int dj = 0; dj < 3; ++dj) {
                    am = fmaf(wm1s[cg][r * 3 + dj], lfm[cv_c][r][cv_j + 3 + dj], am);
                    aa = fmaf(wa1s[cg][r * 3 + dj], fas[cv_c][r][cv_j + 3 + dj], aa);
                }
            }
            m1r[cv_c][cv_j] = am;
            a1r[cv_c][cv_j] = aa;
        }
        __syncthreads();                 // m1r/a1r ready

        // ---- matmul accumulate: 128 FMA/thread ----
        #pragma unroll
        for (int cc = 0; cc < CC; ++cc) {
            float4 mv = *(const float4*)&m1r[cc][l0];
            float4 av = *(const float4*)&a1r[cc][l0];
            float4 wmv = *(const float4*)&w2m[ch0 + cc][o0];
            float4 wav = *(const float4*)&w2a[ch0 + cc][o0];
            FMA_STEP(mv, av, wmv, wav);
        }
    }

    // ---------- epilogue ----------
    #pragma unroll
    for (int oi = 0; oi < 4; ++oi) {
        const int o = o0 + oi;
        float4 mg, oc, os;
        mg.x = __expf(accm[oi].x); mg.y = __expf(accm[oi].y);
        mg.z = __expf(accm[oi].z); mg.w = __expf(accm[oi].w);
        oc.x = mg.x * __cosf(acca[oi].x); os.x = mg.x * __sinf(acca[oi].x);
        oc.y = mg.y * __cosf(acca[oi].y); os.y = mg.y * __sinf(acca[oi].y);
        oc.z = mg.z * __cosf(acca[oi].z); os.z = mg.z * __sinf(acca[oi].z);
        oc.w = mg.w * __cosf(acca[oi].w); os.w = mg.w * __sinf(acca[oi].w);
        size_t gi = ((size_t)(b * 2) * NCOUT + o) * NL + i * 64 + l0;
        *(float4*)&out[gi] = oc;
        *(float4*)&out[gi + (size_t)NCOUT * NL] = os;
    }
}

extern "C" void kernel_launch(void* const* d_in, const int* in_sizes, int n_in,
                              void* d_out, int out_size, void* d_ws, size_t ws_size,
                              hipStream_t stream) {
    const float* x_mag = (const float*)d_in[0];
    const float* x_ang = (const float*)d_in[1];
    const float* w_mag = (const float*)d_in[2];
    const float* w_ang = (const float*)d_in[3];
    const float* w1    = (const float*)d_in[4];
    const float* w2    = (const float*)d_in[5];
    float* out = (float*)d_out;

    fused_kernel<<<NB * 64, 256, 0, stream>>>(x_mag, x_ang, w_mag, w_ang, w1, w2, out);
}

// Round 5
// 39.985 us; speedup vs baseline: 1.2728x; 1.2728x over previous
//
#include <hip/hip_runtime.h>
#include <math.h>

// Problem constants
#define NB 16
#define NC 64
#define NL 4096            // 64*64
#define NCOUT 64
#define EPSF 1e-5f
#define LOG_EPSF -11.512925464970229f   // log(1e-5)
#define CC 4               // channels per chunk (= waves per block)
#define NCHUNK 16

// 16 FMAs: ACC[oi] (l-vector) += MV (l-vector) * W[oi]
#define FMA16(ACC, MV, W) \
  ACC[0].x = fmaf(MV.x, W.x, ACC[0].x); ACC[0].y = fmaf(MV.y, W.x, ACC[0].y); \
  ACC[0].z = fmaf(MV.z, W.x, ACC[0].z); ACC[0].w = fmaf(MV.w, W.x, ACC[0].w); \
  ACC[1].x = fmaf(MV.x, W.y, ACC[1].x); ACC[1].y = fmaf(MV.y, W.y, ACC[1].y); \
  ACC[1].z = fmaf(MV.z, W.y, ACC[1].z); ACC[1].w = fmaf(MV.w, W.y, ACC[1].w); \
  ACC[2].x = fmaf(MV.x, W.z, ACC[2].x); ACC[2].y = fmaf(MV.y, W.z, ACC[2].y); \
  ACC[2].z = fmaf(MV.z, W.z, ACC[2].z); ACC[2].w = fmaf(MV.w, W.z, ACC[2].w); \
  ACC[3].x = fmaf(MV.x, W.w, ACC[3].x); ACC[3].y = fmaf(MV.y, W.w, ACC[3].y); \
  ACC[3].z = fmaf(MV.z, W.w, ACC[3].z); ACC[3].w = fmaf(MV.w, W.w, ACC[3].w);

__global__ __launch_bounds__(256, 2) void fused_kernel(
    const float* __restrict__ x_mag, const float* __restrict__ x_ang,
    const float* __restrict__ wm, const float* __restrict__ wa,
    const float* __restrict__ w1, const float* __restrict__ w2,
    float* __restrict__ out)
{
    // LDS ~60 KB -> exactly 2 blocks/CU; grid 512 = 2/CU single dispatch wave
    __shared__ __align__(16) float lfm[CC][4][72];      // staged log(fm+eps), rows i0-1..i0+2, cols 3..68 valid
    __shared__ __align__(16) float fas[CC][4][72];      // staged fa
    __shared__ __align__(16) float m1r[2][CC][2][64];   // conv out (mag), parity double-buffer
    __shared__ __align__(16) float a1r[2][CC][2][64];   // conv out (ang)
    __shared__ __align__(16) float w2m[64][68];         // [c][o] w2^2/rowsum(o)
    __shared__ __align__(16) float w2a[64][68];         // [c][o] w2^2/globalsum
    __shared__ float wm1s[64][9], wa1s[64][9];          // w1 conv weights
    __shared__ float smag_s[64][9], tang_s[64][9];      // boundary-class sums
    __shared__ float red[4][4];

    const int tid  = threadIdx.x;
    const int lane = tid & 63;
    const int wv   = tid >> 6;

    // XCD swizzle: 512 % 8 == 0 -> bijective; 64 consecutive bids (2 images) per XCD
    const int bid = (blockIdx.x & 7) * 64 + (blockIdx.x >> 3);
    const int b  = bid >> 5;
    const int i0 = (bid & 31) * 2;       // this block owns output rows i0, i0+1

    // ---- stage decode: wave wv stages channel (ch0+wv); lane -> (r, j4) ----
    const int r  = lane >> 4;            // staged row 0..3 -> image row i0-1+r
    const int j4 = lane & 15;            // f4 column
    const int ir = i0 - 1 + r;
    const bool ok = ((unsigned)ir < 64u);
    const int irc = ok ? ir : 0;
    const int ci = (ir == 0) ? 0 : ((ir == 63) ? 2 : 1);
    const int kL = ci * 3 + 0, kC = ci * 3 + 1, kR = ci * 3 + 2;
    const float ni = (ci == 1) ? 3.f : 2.f;
    const float nC = 3.f * ni;
    const float n0 = (j4 == 0)  ? 2.f * ni : nC;
    const float n3 = (j4 == 15) ? 2.f * ni : nC;

    const float* spm = x_mag + ((size_t)(b * NC + wv) * NL + irc * 64 + j4 * 4);
    const float* spa = x_ang + ((size_t)(b * NC + wv) * NL + irc * 64 + j4 * 4);

    // chunk-0 prefetch in flight across the whole weight prep
    float4 pfm = *(const float4*)spm;
    float4 pfa = *(const float4*)spa;

    // ---------- per-block weight prep ----------
    // global square-sums of wm, wa, w1 (576 elements each)
    float p0 = 0.f, p1 = 0.f, p2 = 0.f;
    {
        float v;
        v = wm[tid];       p0 += v * v;  v = wm[tid + 256]; p0 += v * v;
        v = wa[tid];       p1 += v * v;  v = wa[tid + 256]; p1 += v * v;
        v = w1[tid];       p2 += v * v;  v = w1[tid + 256]; p2 += v * v;
        if (tid < 64) {
            v = wm[tid + 512]; p0 += v * v;
            v = wa[tid + 512]; p1 += v * v;
            v = w1[tid + 512]; p2 += v * v;
        }
    }
    #pragma unroll
    for (int s = 32; s; s >>= 1) {
        p0 += __shfl_down(p0, s); p1 += __shfl_down(p1, s); p2 += __shfl_down(p2, s);
    }
    if (lane == 0) { red[0][wv] = p0; red[1][wv] = p1; red[2][wv] = p2; }

    // w2: transposed column loads (lane = c), per-o rowsums via 64-lane butterfly
    float sqv[4][4], r2v[4][4];
    float s22p = 0.f;
    #pragma unroll
    for (int k = 0; k < 4; ++k) {
        const int oq = wv + 4 * k;       // o-quad 0..15 (each handled by one wave/k)
        #pragma unroll
        for (int n = 0; n < 4; ++n) {
            float v = w2[(oq * 4 + n) * 64 + lane];
            float s = v * v;
            sqv[k][n] = s;
            float rr = s;
            rr += __shfl_xor(rr, 1);  rr += __shfl_xor(rr, 2);
            rr += __shfl_xor(rr, 4);  rr += __shfl_xor(rr, 8);
            rr += __shfl_xor(rr, 16); rr += __shfl_xor(rr, 32);
            r2v[k][n] = rr;              // rowsum r2[o], broadcast to all lanes
        }
        s22p += r2v[k][0] + r2v[k][1] + r2v[k][2] + r2v[k][3];
    }
    if (lane == 0) red[3][wv] = s22p;
    __syncthreads();
    const float s_wm2 = red[0][0] + red[0][1] + red[0][2] + red[0][3];
    const float s_wa2 = red[1][0] + red[1][1] + red[1][2] + red[1][3];
    const float s_w12 = red[2][0] + red[2][1] + red[2][2] + red[2][3];
    const float inv_s22 = 1.f / (red[3][0] + red[3][1] + red[3][2] + red[3][3]);

    // write normalized transposed w2 tables: one aligned f4 per (c, o-quad)
    #pragma unroll
    for (int k = 0; k < 4; ++k) {
        const int oq = wv + 4 * k;
        float4 wmv4, wav4;
        wmv4.x = sqv[k][0] / r2v[k][0];  wav4.x = sqv[k][0] * inv_s22;
        wmv4.y = sqv[k][1] / r2v[k][1];  wav4.y = sqv[k][1] * inv_s22;
        wmv4.z = sqv[k][2] / r2v[k][2];  wav4.z = sqv[k][2] * inv_s22;
        wmv4.w = sqv[k][3] / r2v[k][3];  wav4.w = sqv[k][3] * inv_s22;
        *(float4*)&w2m[lane][oq * 4] = wmv4;
        *(float4*)&w2a[lane][oq * 4] = wav4;
    }

    // w1 tables (wave 0) and boundary-class tables (wave 1)
    if (tid < 64) {
        const int c = tid;
        float q[9]; float r1c = 0.f;
        #pragma unroll
        for (int k = 0; k < 9; ++k) { float v = w1[c * 9 + k]; q[k] = v * v; r1c += q[k]; }
        float inv_r = 1.f / r1c, inv_s = 1.f / s_w12;
        #pragma unroll
        for (int k = 0; k < 9; ++k) { wm1s[c][k] = q[k] * inv_r; wa1s[c][k] = q[k] * inv_s; }
    } else if (tid < 128) {
        const int c = tid - 64;
        float nm[9], na[9];
        const float inv_m = 1.f / s_wm2, inv_a = 1.f / s_wa2;
        #pragma unroll
        for (int k = 0; k < 9; ++k) {
            float v = wm[c * 9 + k];
            nm[k] = v * v * inv_m;
            na[k] = wa[c * 9 + k] * inv_a;
        }
        #pragma unroll
        for (int ci_ = 0; ci_ < 3; ++ci_) {
            #pragma unroll
            for (int cj = 0; cj < 3; ++cj) {
                float sm = 0.f, sa = 0.f;
                #pragma unroll
                for (int ki = 0; ki < 3; ++ki) {
                    bool vi = (ci_ == 0) ? (ki < 2) : ((ci_ == 2) ? (ki > 0) : true);
                    if (!vi) continue;
                    #pragma unroll
                    for (int kj = 0; kj < 3; ++kj) {
                        bool vj = (cj == 0) ? (kj < 2) : ((cj == 2) ? (kj > 0) : true);
                        if (!vj) continue;
                        sm += nm[ki * 3 + kj];
                        sa += na[ki * 3 + kj];
                    }
                }
                smag_s[c][ci_ * 3 + cj] = sm;
                tang_s[c][ci_ * 3 + cj] = sa;
            }
        }
    }
    __syncthreads();

    // ---------- main channel loop ----------
    const int l0 = (tid & 15) * 4;       // matmul: l columns
    const int o0 = (tid >> 4) * 4;       // matmul: o rows

    float4 accm[2][4], acca[2][4];       // [row][oi], all indices compile-time
    #pragma unroll
    for (int rr = 0; rr < 2; ++rr)
        #pragma unroll
        for (int oi = 0; oi < 4; ++oi) {
            accm[rr][oi].x = accm[rr][oi].y = accm[rr][oi].z = accm[rr][oi].w = 0.f;
            acca[rr][oi].x = acca[rr][oi].y = acca[rr][oi].z = acca[rr][oi].w = 0.f;
        }

    auto do_matmul = [&](int chm, int pp) {
        const int c0 = chm * CC;
        #pragma unroll
        for (int cc = 0; cc < CC; ++cc) {
            float4 mv0 = *(const float4*)&m1r[pp][cc][0][l0];
            float4 mv1 = *(const float4*)&m1r[pp][cc][1][l0];
            float4 av0 = *(const float4*)&a1r[pp][cc][0][l0];
            float4 av1 = *(const float4*)&a1r[pp][cc][1][l0];
            float4 wmv = *(const float4*)&w2m[c0 + cc][o0];
            float4 wav = *(const float4*)&w2a[c0 + cc][o0];
            FMA16(accm[0], mv0, wmv);
            FMA16(accm[1], mv1, wmv);
            FMA16(acca[0], av0, wav);
            FMA16(acca[1], av1, wav);
        }
    };

    #pragma unroll 2
    for (int ch = 0; ch < NCHUNK; ++ch) {
        const int p = ch & 1;

        // matmul for previous chunk (reads m1r[p^1]; fenced by prev barrier)
        if (ch > 0) do_matmul(ch - 1, p ^ 1);

        // stage(ch): wave-local -> no barrier before conv
        {
            const int cg = ch * CC + wv;
            float4 dm, da;
            if (ok) {
                float sC = smag_s[cg][kC], tC = tang_s[cg][kC];
                float s0 = (j4 == 0)  ? smag_s[cg][kL] : sC;
                float s3 = (j4 == 15) ? smag_s[cg][kR] : sC;
                float t0 = (j4 == 0)  ? tang_s[cg][kL] : tC;
                float t3 = (j4 == 15) ? tang_s[cg][kR] : tC;
                dm.x = __logf(fmaf(n0, pfm.x, s0) + EPSF);
                dm.y = __logf(fmaf(nC, pfm.y, sC) + EPSF);
                dm.z = __logf(fmaf(nC, pfm.z, sC) + EPSF);
                dm.w = __logf(fmaf(n3, pfm.w, s3) + EPSF);
                da.x = pfa.x * t0; da.y = pfa.y * tC;
                da.z = pfa.z * tC; da.w = pfa.w * t3;
            } else {
                dm.x = dm.y = dm.z = dm.w = LOG_EPSF;
                da.x = da.y = da.z = da.w = 0.f;
            }
            *(float4*)&lfm[wv][r][4 + j4 * 4] = dm;
            *(float4*)&fas[wv][r][4 + j4 * 4] = da;
            if (j4 == 0)  { lfm[wv][r][3]  = LOG_EPSF; fas[wv][r][3]  = 0.f; }
            if (j4 == 15) { lfm[wv][r][68] = LOG_EPSF; fas[wv][r][68] = 0.f; }
        }

        // prefetch next chunk (latency hides under conv + barrier + matmul)
        if (ch + 1 < NCHUNK) {
            pfm = *(const float4*)(spm + (size_t)(ch + 1) * CC * NL);
            pfa = *(const float4*)(spa + (size_t)(ch + 1) * CC * NL);
        }

        // conv(ch): wave wv convolves its own staged channel -> m1r[p]
        {
            const int cg = ch * CC + wv;
            float mres0 = 0.f, mres1 = 0.f, ares0 = 0.f, ares1 = 0.f;
            #pragma unroll
            for (int r_ = 0; r_ < 4; ++r_) {
                float l0v = lfm[wv][r_][lane + 3];
                float l1v = lfm[wv][r_][lane + 4];
                float l2v = lfm[wv][r_][lane + 5];
                float a0v = fas[wv][r_][lane + 3];
                float a1v = fas[wv][r_][lane + 4];
                float a2v = fas[wv][r_][lane + 5];
                if (r_ < 3) {   // output row i0 (rr=0), ki = r_
                    mres0 = fmaf(wm1s[cg][r_ * 3 + 0], l0v, mres0);
                    mres0 = fmaf(wm1s[cg][r_ * 3 + 1], l1v, mres0);
                    mres0 = fmaf(wm1s[cg][r_ * 3 + 2], l2v, mres0);
                    ares0 = fmaf(wa1s[cg][r_ * 3 + 0], a0v, ares0);
                    ares0 = fmaf(wa1s[cg][r_ * 3 + 1], a1v, ares0);
                    ares0 = fmaf(wa1s[cg][r_ * 3 + 2], a2v, ares0);
                }
                if (r_ > 0) {   // output row i0+1 (rr=1), ki = r_-1
                    const int ki = r_ - 1;
                    mres1 = fmaf(wm1s[cg][ki * 3 + 0], l0v, mres1);
                    mres1 = fmaf(wm1s[cg][ki * 3 + 1], l1v, mres1);
                    mres1 = fmaf(wm1s[cg][ki * 3 + 2], l2v, mres1);
                    ares1 = fmaf(wa1s[cg][ki * 3 + 0], a0v, ares1);
                    ares1 = fmaf(wa1s[cg][ki * 3 + 1], a1v, ares1);
                    ares1 = fmaf(wa1s[cg][ki * 3 + 2], a2v, ares1);
                }
            }
            m1r[p][wv][0][lane] = mres0;
            m1r[p][wv][1][lane] = mres1;
            a1r[p][wv][0][lane] = ares0;
            a1r[p][wv][1][lane] = ares1;
        }
        __syncthreads();   // the ONE barrier per chunk (fences m1r[p])
    }
    do_matmul(NCHUNK - 1, 1);

    // ---------- epilogue ----------
    #pragma unroll
    for (int rr = 0; rr < 2; ++rr) {
        #pragma unroll
        for (int oi = 0; oi < 4; ++oi) {
            float4 am = accm[rr][oi], aa = acca[rr][oi];
            float4 oc, os;
            float ex;
            ex = __expf(am.x); oc.x = ex * __cosf(aa.x); os.x = ex * __sinf(aa.x);
            ex = __expf(am.y); oc.y = ex * __cosf(aa.y); os.y = ex * __sinf(aa.y);
            ex = __expf(am.z); oc.z = ex * __cosf(aa.z); os.z = ex * __sinf(aa.z);
            ex = __expf(am.w); oc.w = ex * __cosf(aa.w); os.w = ex * __sinf(aa.w);
            size_t gi = ((size_t)(b * 2) * NCOUT + o0 + oi) * NL + (size_t)(i0 + rr) * 64 + l0;
            *(float4*)&out[gi] = oc;
            *(float4*)&out[gi + (size_t)NCOUT * NL] = os;
        }
    }
}

extern "C" void kernel_launch(void* const* d_in, const int* in_sizes, int n_in,
                              void* d_out, int out_size, void* d_ws, size_t ws_size,
                              hipStream_t stream) {
    const float* x_mag = (const float*)d_in[0];
    const float* x_ang = (const float*)d_in[1];
    const float* w_mag = (const float*)d_in[2];
    const float* w_ang = (const float*)d_in[3];
    const float* w1    = (const float*)d_in[4];
    const float* w2    = (const float*)d_in[5];
    float* out = (float*)d_out;

    fused_kernel<<<NB * 32, 256, 0, stream>>>(x_mag, x_ang, w_mag, w_ang, w1, w2, out);
}